// Round 6
// baseline (41.685 us; speedup 1.0000x reference)
//
#include <hip/hip_runtime.h>
#include <hip/hip_bf16.h>

#define N_ATOMS 51200

// Output layout (flat, reference return order):
//   energy[512]@0, forces[153600]@512, stress[4608]@154112,
//   energy_uncert[512]@158720 (=0.6), force_uncert[153600]@159232 (computed),
//   stress_uncert[4608]@312832 (=0.1/16)
#define OUT_FUNC   159232
#define COPY_TOTAL 163840

typedef __attribute__((ext_vector_type(4))) float f32x4;
typedef __attribute__((ext_vector_type(4))) short s16x4;
typedef __attribute__((ext_vector_type(8))) short s16x8;

constexpr int BLK = 256;

__device__ __forceinline__ short f2bf(float x) {
    union { __hip_bfloat16 b; short s; } u;
    u.b = __float2bfloat16(x);            // RNE
    return u.s;
}
__device__ __forceinline__ float silu_(float v) { return v / (1.0f + __expf(-v)); }
__device__ __forceinline__ s16x8 cvt8(f32x4 lo, f32x4 hi) {
    s16x8 f;
    f[0]=f2bf(lo.x); f[1]=f2bf(lo.y); f[2]=f2bf(lo.z); f[3]=f2bf(lo.w);
    f[4]=f2bf(hi.x); f[5]=f2bf(hi.y); f[6]=f2bf(hi.z); f[7]=f2bf(hi.w);
    return f;
}

__global__ __launch_bounds__(BLK, 4) void funcert_kernel(
    const float* __restrict__ nf,
    const float* __restrict__ energy,
    const float* __restrict__ forces,
    const float* __restrict__ stress,
    const float* __restrict__ W1f, const float* __restrict__ b1f,
    const float* __restrict__ W2f, const float* __restrict__ b2f,
    const float* __restrict__ W3f, const float* __restrict__ b3f,
    float* __restrict__ out)
{
    const int t   = threadIdx.x;
    const int gid = blockIdx.x * BLK + t;

    // ---- passthrough / constant outputs (exact, verified R1-R5) ----
    if (gid < COPY_TOTAL) {
        float v; int o = gid;
        if      (gid < 512)    { v = energy[gid]; }
        else if (gid < 154112) { v = forces[gid - 512]; }
        else if (gid < 158720) { v = stress[gid - 154112]; }
        else if (gid < 159232) { v = 0.6f; }
        else                   { v = 0.1f / 16.0f; o = gid + 153600; }
        out[o] = v;
    }

    // wave-private LDS: 4 waves x 8 KB (16 atom-rows x 256 bf16, swizzled 16B slots)
    __shared__ short Xs[4 * 4096];   // 32 KB total

    const int lane  = t & 63;
    const int w     = t >> 6;
    const int g     = lane >> 4;     // k-subgroup
    const int col   = lane & 15;     // A row / B col / D col
    const int awave = blockIdx.x * 64 + w * 16;   // this wave's 16 atoms

    short* Xw = Xs + w * 4096;       // wave-private 8 KB

    // ---- stage this wave's 16 rows: f32 coalesced -> bf16 -> swizzled LDS ----
    // lane = f4-column of one row; concat handled by g4 (cols [0:32) U [64:96))
    const int g4 = lane + (lane >= 32 ? 32 : 0);
    const int sp_lo = (lane >> 1);                 // slot base; ^(row&7) per row
    {
        f32x4 xv[8];
        #pragma unroll
        for (int b = 0; b < 2; ++b) {              // two batches of 8 rows
            #pragma unroll
            for (int i = 0; i < 8; ++i) {
                const int r = b * 8 + i;
                xv[i] = ((const f32x4*)nf)[(size_t)(awave + r) * 96 + g4];
            }
            #pragma unroll
            for (int i = 0; i < 8; ++i) {
                const int r  = b * 8 + i;
                const int sp = sp_lo ^ (r & 7);
                s16x4 bb;
                bb.x = f2bf(xv[i].x); bb.y = f2bf(xv[i].y);
                bb.z = f2bf(xv[i].z); bb.w = f2bf(xv[i].w);
                *(s16x4*)(Xw + r * 256 + sp * 8 + (lane & 1) * 4) = bb;
            }
        }
    }

    // ---- A-fragments: row = col (atom within wave tile), 8 k-steps ----
    s16x8 afrag[8];
    #pragma unroll
    for (int ks = 0; ks < 8; ++ks) {
        const int sp = (ks * 4 + g) ^ (col & 7);
        afrag[ks] = *(const s16x8*)(Xw + col * 256 + sp * 8);
    }

    short* Hw = Xw;                  // reuse wave-private LDS for h1 (2 KB)

    // ---- L1: 4 N-tiles of 16 out-ch, K=256; W1f streamed from L1/L2 ----
    #pragma unroll
    for (int nt = 0; nt < 4; ++nt) {
        const int ch = nt * 16 + col;
        f32x4 acc = {0.f, 0.f, 0.f, 0.f};
        #pragma unroll
        for (int h = 0; h < 2; ++h) {
            f32x4 bv[8];
            #pragma unroll
            for (int k4 = 0; k4 < 4; ++k4) {
                const int ks = h * 4 + k4;
                const float* p = W1f + ch * 256 + ks * 32 + g * 8;
                bv[2 * k4]     = *(const f32x4*)p;
                bv[2 * k4 + 1] = *(const f32x4*)(p + 4);
            }
            #pragma unroll
            for (int k4 = 0; k4 < 4; ++k4)
                acc = __builtin_amdgcn_mfma_f32_16x16x32_bf16(
                        afrag[h * 4 + k4], cvt8(bv[2 * k4], bv[2 * k4 + 1]), acc, 0, 0, 0);
        }
        const float b1v = b1f[ch];
        // D: lane holds (atom = g*4+r, ch); h1 bf16 with XOR-16B swizzle per row
        #pragma unroll
        for (int r = 0; r < 4; ++r) {
            const int a = g * 4 + r;
            *(short*)((char*)Hw + a * 128 + ((ch * 2) ^ ((a & 7) << 4))) =
                f2bf(silu_(acc[r] + b1v));
        }
    }

    // ---- L2: 16 out-ch, K=64; A2 from swizzled LDS, B2 from W2f ----
    f32x4 acc2 = {0.f, 0.f, 0.f, 0.f};
    #pragma unroll
    for (int ks2 = 0; ks2 < 2; ++ks2) {
        const float* p = W2f + col * 64 + ks2 * 32 + g * 8;  // B2[k][n] = W2f[n][k]
        const s16x8 bf2 = cvt8(*(const f32x4*)p, *(const f32x4*)(p + 4));
        const s16x8 af2 = *(const s16x8*)((char*)Hw + col * 128 +
                                          ((ks2 * 64 + g * 16) ^ ((col & 7) << 4)));
        acc2 = __builtin_amdgcn_mfma_f32_16x16x32_bf16(af2, bf2, acc2, 0, 0, 0);
    }

    // ---- h2 + L3 + exp: lane owns ch2=col for atoms g*4+r ----
    const float b2v = b2f[col];
    const float w3v = W3f[col];
    float y[4];
    #pragma unroll
    for (int r = 0; r < 4; ++r)
        y[r] = silu_(acc2[r] + b2v) * w3v;
    #pragma unroll
    for (int m = 1; m < 16; m <<= 1) {
        #pragma unroll
        for (int r = 0; r < 4; ++r)
            y[r] += __shfl_xor(y[r], m, 64);   // reduce over 16 cols
    }
    const float b3v = b3f[0];
    float fu[4];
    #pragma unroll
    for (int r = 0; r < 4; ++r)
        fu[r] = __expf(y[r] + b3v) * 0.1f;

    if (col < 12) {                            // 4 atoms x 3 comps per 16-lane group
        const int a_ = col / 3, c = col - a_ * 3;
        const float v = (a_ == 0) ? fu[0] : (a_ == 1) ? fu[1] : (a_ == 2) ? fu[2] : fu[3];
        out[OUT_FUNC + 3 * (awave + g * 4 + a_) + c] = v;
    }
}

extern "C" void kernel_launch(void* const* d_in, const int* in_sizes, int n_in,
                              void* d_out, int out_size, void* d_ws, size_t ws_size,
                              hipStream_t stream) {
    const float* nf     = (const float*)d_in[0];
    const float* energy = (const float*)d_in[1];
    const float* forces = (const float*)d_in[2];
    const float* stress = (const float*)d_in[3];
    const float* W1f    = (const float*)d_in[10];
    const float* b1f    = (const float*)d_in[11];
    const float* W2f    = (const float*)d_in[12];
    const float* b2f    = (const float*)d_in[13];
    const float* W3f    = (const float*)d_in[14];
    const float* b3f    = (const float*)d_in[15];
    float* out = (float*)d_out;

    dim3 grid(N_ATOMS / 64);   // 800 blocks, 4 fully independent waves each
    funcert_kernel<<<grid, BLK, 0, stream>>>(nf, energy, forces, stress,
                                             W1f, b1f, W2f, b2f, W3f, b3f, out);
}

// Round 7
// 22.788 us; speedup vs baseline: 1.8292x; 1.8292x over previous
//
#include <hip/hip_runtime.h>
#include <hip/hip_bf16.h>

#define N_ATOMS 51200

// Output layout (flat floats, reference return order):
//   energy[512]@0, forces[153600]@512, stress[4608]@154112,
//   energy_uncert[512]@158720 (=0.6), force_uncert[153600]@159232 (computed),
//   stress_uncert[4608]@312832 (=0.1/16)
#define OUT_FUNC 159232

typedef __attribute__((ext_vector_type(4))) float f32x4;
typedef __attribute__((ext_vector_type(4))) short s16x4;
typedef __attribute__((ext_vector_type(8))) short s16x8;

constexpr int BLK = 256;

__device__ __forceinline__ short f2bf(float x) {
    union { __hip_bfloat16 b; short s; } u;
    u.b = __float2bfloat16(x);            // RNE
    return u.s;
}
__device__ __forceinline__ float silu_(float v) { return v / (1.0f + __expf(-v)); }
__device__ __forceinline__ s16x8 cvt8(f32x4 lo, f32x4 hi) {
    s16x8 f;
    f[0]=f2bf(lo.x); f[1]=f2bf(lo.y); f[2]=f2bf(lo.z); f[3]=f2bf(lo.w);
    f[4]=f2bf(hi.x); f[5]=f2bf(hi.y); f[6]=f2bf(hi.z); f[7]=f2bf(hi.w);
    return f;
}

__global__ __launch_bounds__(BLK, 5) void funcert_kernel(
    const float* __restrict__ nf,
    const float* __restrict__ energy,
    const float* __restrict__ forces,
    const float* __restrict__ stress,
    const float* __restrict__ W1f, const float* __restrict__ b1f,
    const float* __restrict__ W2f, const float* __restrict__ b2f,
    const float* __restrict__ W3f, const float* __restrict__ b3f,
    float* __restrict__ out)
{
    const int t   = threadIdx.x;
    const int gid = blockIdx.x * BLK + t;

    // ---- passthrough / constant outputs as float4 (all segments f4-aligned) ----
    if (gid < 40960) {
        f32x4 v; int o = gid;
        if      (gid < 128)   { v = ((const f32x4*)energy)[gid]; }
        else if (gid < 38528) { v = ((const f32x4*)forces)[gid - 128]; }
        else if (gid < 39680) { v = ((const f32x4*)stress)[gid - 38528]; }
        else if (gid < 39808) { v = (f32x4){0.6f, 0.6f, 0.6f, 0.6f}; }
        else { v = (f32x4){0.00625f, 0.00625f, 0.00625f, 0.00625f}; o = gid + 38400; }
        ((f32x4*)out)[o] = v;
    }

    __shared__ short Xs[64 * 128];   // 16 KB: half-K X tile bf16 (64 rows x 128), swizzled 16B slots
    __shared__ short H1s[64 * 64];   // 8 KB: h1 bf16, row=atom (128B), same as R3

    const int lane  = t & 63;
    const int w     = t >> 6;
    const int g     = lane >> 4;     // k-subgroup
    const int col   = lane & 15;     // A row / B col / D col
    const int abase = blockIdx.x * 64;

    const int ch  = w * 16 + col;
    const float b1v = b1f[ch];

    const int c4  = lane & 31;       // f4 column within the half-row
    const int sub = lane >> 5;       // row-pair sub-index

    f32x4 acc[4];
    #pragma unroll
    for (int mt = 0; mt < 4; ++mt) acc[mt] = (f32x4){0.f, 0.f, 0.f, 0.f};

    #pragma unroll 1
    for (int h = 0; h < 2; ++h) {
        // ---- stage half h: 8 instrs/wave, 2 rows (2x512B) per instr ----
        #pragma unroll
        for (int i = 0; i < 8; ++i) {
            const int r = i * 8 + w * 2 + sub;
            const f32x4 x = ((const f32x4*)nf)[(size_t)(abase + r) * 96 + h * 64 + c4];
            const int sp = (c4 >> 1) ^ (r & 7);      // 16B-slot XOR swizzle
            s16x4 bb;
            bb.x = f2bf(x.x); bb.y = f2bf(x.y); bb.z = f2bf(x.z); bb.w = f2bf(x.w);
            *(s16x4*)(Xs + r * 128 + sp * 8 + (lane & 1) * 4) = bb;
        }

        // ---- issue this half's W1f loads before the barrier (L2 latency hides) ----
        f32x4 wv[8];
        #pragma unroll
        for (int ks = 0; ks < 4; ++ks) {
            const float* p = W1f + ch * 256 + h * 128 + ks * 32 + g * 8;
            wv[2 * ks]     = *(const f32x4*)p;
            wv[2 * ks + 1] = *(const f32x4*)(p + 4);
        }
        __syncthreads();              // Xs half ready

        s16x8 wf[4];
        #pragma unroll
        for (int ks = 0; ks < 4; ++ks) wf[ks] = cvt8(wv[2 * ks], wv[2 * ks + 1]);

        // ---- L1 compute on this half: 4 M-tiles x 4 k-steps ----
        #pragma unroll
        for (int mt = 0; mt < 4; ++mt) {
            const int row = mt * 16 + col;           // A row = atom
            #pragma unroll
            for (int ks = 0; ks < 4; ++ks) {
                const int sl = (ks * 4 + g) ^ (row & 7);
                const s16x8 af = *(const s16x8*)(Xs + row * 128 + sl * 8);
                acc[mt] = __builtin_amdgcn_mfma_f32_16x16x32_bf16(af, wf[ks], acc[mt], 0, 0, 0);
            }
        }
        if (h == 0) __syncthreads();  // all waves done reading half 0 before restage
    }

    // ---- bias + silu -> h1 (layout identical to R3) ----
    #pragma unroll
    for (int mt = 0; mt < 4; ++mt) {
        #pragma unroll
        for (int r = 0; r < 4; ++r) {
            const int atom = mt * 16 + g * 4 + r;
            H1s[atom * 64 + ch] = f2bf(silu_(acc[mt][r] + b1v));
        }
    }
    __syncthreads();

    // ---- L2: wave w -> atoms [16w,16w+16), 2 k-steps over 64 ch ----
    s16x8 w2frag[2];
    #pragma unroll
    for (int ks = 0; ks < 2; ++ks) {
        const float* p = W2f + col * 64 + ks * 32 + g * 8;   // B2[k][n] = W2f[n][k]
        w2frag[ks] = cvt8(*(const f32x4*)p, *(const f32x4*)(p + 4));
    }
    const int arow = w * 16 + col;
    f32x4 a2 = {0.f, 0.f, 0.f, 0.f};
    #pragma unroll
    for (int ks = 0; ks < 2; ++ks) {
        const s16x8 af = *(const s16x8*)(H1s + arow * 64 + ks * 32 + g * 8);
        a2 = __builtin_amdgcn_mfma_f32_16x16x32_bf16(af, w2frag[ks], a2, 0, 0, 0);
    }

    // ---- h2 + L3 + exp: lane owns ch2=col for atoms 16w + g*4 + r ----
    const float b2v = b2f[col];
    const float w3v = W3f[col];
    float y[4];
    #pragma unroll
    for (int r = 0; r < 4; ++r)
        y[r] = silu_(a2[r] + b2v) * w3v;
    #pragma unroll
    for (int m = 1; m < 16; m <<= 1) {
        #pragma unroll
        for (int r = 0; r < 4; ++r)
            y[r] += __shfl_xor(y[r], m, 64);   // reduce over 16 cols
    }
    const float b3v = b3f[0];
    float fu[4];
    #pragma unroll
    for (int r = 0; r < 4; ++r)
        fu[r] = __expf(y[r] + b3v) * 0.1f;

    if (col < 12) {                            // 4 atoms x 3 comps per 16-lane group
        const int a_ = col / 3, c = col - a_ * 3;
        const float v = (a_ == 0) ? fu[0] : (a_ == 1) ? fu[1] : (a_ == 2) ? fu[2] : fu[3];
        const int atom = w * 16 + g * 4 + a_;
        out[OUT_FUNC + 3 * (abase + atom) + c] = v;
    }
}

extern "C" void kernel_launch(void* const* d_in, const int* in_sizes, int n_in,
                              void* d_out, int out_size, void* d_ws, size_t ws_size,
                              hipStream_t stream) {
    const float* nf     = (const float*)d_in[0];
    const float* energy = (const float*)d_in[1];
    const float* forces = (const float*)d_in[2];
    const float* stress = (const float*)d_in[3];
    const float* W1f    = (const float*)d_in[10];
    const float* b1f    = (const float*)d_in[11];
    const float* W2f    = (const float*)d_in[12];
    const float* b2f    = (const float*)d_in[13];
    const float* W3f    = (const float*)d_in[14];
    const float* b3f    = (const float*)d_in[15];
    float* out = (float*)d_out;

    dim3 grid(N_ATOMS / 64);   // 800 blocks
    funcert_kernel<<<grid, BLK, 0, stream>>>(nf, energy, forces, stress,
                                             W1f, b1f, W2f, b2f, W3f, b3f, out);
}

// Round 8
// 21.784 us; speedup vs baseline: 1.9136x; 1.0461x over previous
//
#include <hip/hip_runtime.h>
#include <hip/hip_bf16.h>

#define N_ATOMS 51200

// Output layout (flat floats, reference return order):
//   energy[512]@0, forces[153600]@512, stress[4608]@154112,
//   energy_uncert[512]@158720 (=0.6), force_uncert[153600]@159232 (computed),
//   stress_uncert[4608]@312832 (=0.1/16)
#define OUT_FUNC 159232

typedef __attribute__((ext_vector_type(4))) float f32x4;
typedef __attribute__((ext_vector_type(4))) short s16x4;
typedef __attribute__((ext_vector_type(8))) short s16x8;

constexpr int BLK = 256;

__device__ __forceinline__ short f2bf(float x) {
    union { __hip_bfloat16 b; short s; } u;
    u.b = __float2bfloat16(x);            // RNE
    return u.s;
}
__device__ __forceinline__ float silu_(float v) { return v / (1.0f + __expf(-v)); }
__device__ __forceinline__ s16x8 cvt8(f32x4 lo, f32x4 hi) {
    s16x8 f;
    f[0]=f2bf(lo.x); f[1]=f2bf(lo.y); f[2]=f2bf(lo.z); f[3]=f2bf(lo.w);
    f[4]=f2bf(hi.x); f[5]=f2bf(hi.y); f[6]=f2bf(hi.z); f[7]=f2bf(hi.w);
    return f;
}

__global__ __launch_bounds__(BLK, 5) void funcert_kernel(
    const float* __restrict__ nf,
    const float* __restrict__ energy,
    const float* __restrict__ forces,
    const float* __restrict__ stress,
    const float* __restrict__ W1f, const float* __restrict__ b1f,
    const float* __restrict__ W2f, const float* __restrict__ b2f,
    const float* __restrict__ W3f, const float* __restrict__ b3f,
    float* __restrict__ out)
{
    const int t   = threadIdx.x;
    const int gid = blockIdx.x * BLK + t;

    __shared__ short Xs[64 * 128];   // 16 KB: half-K X tile bf16 (64 x 128), swizzled 16B slots
    __shared__ short H1s[64 * 64];   // 8 KB: h1 bf16, row=atom (128B)

    const int lane  = t & 63;
    const int w     = t >> 6;
    const int g     = lane >> 4;     // k-subgroup
    const int col   = lane & 15;     // A row / B col / D col
    const int abase = blockIdx.x * 64;

    const int ch  = w * 16 + col;
    const int c4  = lane & 31;       // f4 column within the half-row
    const int sub = lane >> 5;       // row-pair sub-index
    const int spb = c4 >> 1;         // 16B-slot base (^ (r&7) per row)

    // ---- issue W0 loads first (arrive while X0 in flight) ----
    f32x4 wv[8];
    #pragma unroll
    for (int ks = 0; ks < 4; ++ks) {
        const float* p = W1f + ch * 256 + ks * 32 + g * 8;
        wv[2 * ks]     = *(const f32x4*)p;
        wv[2 * ks + 1] = *(const f32x4*)(p + 4);
    }

    // ---- issue X0 staging loads ----
    f32x4 xv[8];
    #pragma unroll
    for (int i = 0; i < 8; ++i) {
        const int r = i * 8 + w * 2 + sub;
        xv[i] = ((const f32x4*)nf)[(size_t)(abase + r) * 96 + c4];      // half 0
    }

    // ---- passthrough / constant outputs as float4 (overlaps with loads) ----
    if (gid < 40960) {
        f32x4 v; int o = gid;
        if      (gid < 128)   { v = ((const f32x4*)energy)[gid]; }
        else if (gid < 38528) { v = ((const f32x4*)forces)[gid - 128]; }
        else if (gid < 39680) { v = ((const f32x4*)stress)[gid - 38528]; }
        else if (gid < 39808) { v = (f32x4){0.6f, 0.6f, 0.6f, 0.6f}; }
        else { v = (f32x4){0.00625f, 0.00625f, 0.00625f, 0.00625f}; o = gid + 38400; }
        ((f32x4*)out)[o] = v;
    }

    const float b1v = b1f[ch];

    // ---- cvt W0 -> wf0 (frees wv before xv1 goes live) ----
    s16x8 wf0[4];
    #pragma unroll
    for (int ks = 0; ks < 4; ++ks) wf0[ks] = cvt8(wv[2 * ks], wv[2 * ks + 1]);

    // ---- cvt X0 + swizzled LDS write ----
    #pragma unroll
    for (int i = 0; i < 8; ++i) {
        const int r  = i * 8 + w * 2 + sub;
        const int sp = spb ^ (r & 7);
        s16x4 bb;
        bb.x = f2bf(xv[i].x); bb.y = f2bf(xv[i].y);
        bb.z = f2bf(xv[i].z); bb.w = f2bf(xv[i].w);
        *(s16x4*)(Xs + r * 128 + sp * 8 + (lane & 1) * 4) = bb;
    }
    __syncthreads();                 // (1) Xs = half 0 ready

    // ---- issue X1 loads NOW: latency hides under half-0 compute ----
    #pragma unroll
    for (int i = 0; i < 8; ++i) {
        const int r = i * 8 + w * 2 + sub;
        xv[i] = ((const f32x4*)nf)[(size_t)(abase + r) * 96 + 64 + c4]; // half 1
    }

    // ---- compute half 0: 4 M-tiles x 4 k-steps ----
    f32x4 acc[4];
    #pragma unroll
    for (int mt = 0; mt < 4; ++mt) acc[mt] = (f32x4){0.f, 0.f, 0.f, 0.f};
    #pragma unroll
    for (int mt = 0; mt < 4; ++mt) {
        const int row = mt * 16 + col;
        #pragma unroll
        for (int ks = 0; ks < 4; ++ks) {
            const int sl = (ks * 4 + g) ^ (row & 7);
            const s16x8 af = *(const s16x8*)(Xs + row * 128 + sl * 8);
            acc[mt] = __builtin_amdgcn_mfma_f32_16x16x32_bf16(af, wf0[ks], acc[mt], 0, 0, 0);
        }
    }
    __syncthreads();                 // (2) all waves done reading half 0

    // ---- W1 loads (hidden under X1 cvt/write + barrier) ----
    #pragma unroll
    for (int ks = 0; ks < 4; ++ks) {
        const float* p = W1f + ch * 256 + 128 + ks * 32 + g * 8;
        wv[2 * ks]     = *(const f32x4*)p;
        wv[2 * ks + 1] = *(const f32x4*)(p + 4);
    }

    // ---- cvt X1 + swizzled LDS write (overwrites Xs) ----
    #pragma unroll
    for (int i = 0; i < 8; ++i) {
        const int r  = i * 8 + w * 2 + sub;
        const int sp = spb ^ (r & 7);
        s16x4 bb;
        bb.x = f2bf(xv[i].x); bb.y = f2bf(xv[i].y);
        bb.z = f2bf(xv[i].z); bb.w = f2bf(xv[i].w);
        *(s16x4*)(Xs + r * 128 + sp * 8 + (lane & 1) * 4) = bb;
    }
    s16x8 wf1[4];
    #pragma unroll
    for (int ks = 0; ks < 4; ++ks) wf1[ks] = cvt8(wv[2 * ks], wv[2 * ks + 1]);
    __syncthreads();                 // (3) Xs = half 1 ready

    // ---- compute half 1 ----
    #pragma unroll
    for (int mt = 0; mt < 4; ++mt) {
        const int row = mt * 16 + col;
        #pragma unroll
        for (int ks = 0; ks < 4; ++ks) {
            const int sl = (ks * 4 + g) ^ (row & 7);
            const s16x8 af = *(const s16x8*)(Xs + row * 128 + sl * 8);
            acc[mt] = __builtin_amdgcn_mfma_f32_16x16x32_bf16(af, wf1[ks], acc[mt], 0, 0, 0);
        }
    }

    // ---- bias + silu -> h1 (layout identical to R3/R7) ----
    #pragma unroll
    for (int mt = 0; mt < 4; ++mt) {
        #pragma unroll
        for (int r = 0; r < 4; ++r) {
            const int atom = mt * 16 + g * 4 + r;
            H1s[atom * 64 + ch] = f2bf(silu_(acc[mt][r] + b1v));
        }
    }
    __syncthreads();

    // ---- L2: wave w -> atoms [16w,16w+16), 2 k-steps over 64 ch ----
    s16x8 w2frag[2];
    #pragma unroll
    for (int ks = 0; ks < 2; ++ks) {
        const float* p = W2f + col * 64 + ks * 32 + g * 8;   // B2[k][n] = W2f[n][k]
        w2frag[ks] = cvt8(*(const f32x4*)p, *(const f32x4*)(p + 4));
    }
    const int arow = w * 16 + col;
    f32x4 a2 = {0.f, 0.f, 0.f, 0.f};
    #pragma unroll
    for (int ks = 0; ks < 2; ++ks) {
        const s16x8 af = *(const s16x8*)(H1s + arow * 64 + ks * 32 + g * 8);
        a2 = __builtin_amdgcn_mfma_f32_16x16x32_bf16(af, w2frag[ks], a2, 0, 0, 0);
    }

    // ---- h2 + L3 + exp: lane owns ch2=col for atoms 16w + g*4 + r ----
    const float b2v = b2f[col];
    const float w3v = W3f[col];
    float y[4];
    #pragma unroll
    for (int r = 0; r < 4; ++r)
        y[r] = silu_(a2[r] + b2v) * w3v;
    #pragma unroll
    for (int m = 1; m < 16; m <<= 1) {
        #pragma unroll
        for (int r = 0; r < 4; ++r)
            y[r] += __shfl_xor(y[r], m, 64);   // reduce over 16 cols
    }
    const float b3v = b3f[0];
    float fu[4];
    #pragma unroll
    for (int r = 0; r < 4; ++r)
        fu[r] = __expf(y[r] + b3v) * 0.1f;

    if (col < 12) {                            // 4 atoms x 3 comps per 16-lane group
        const int a_ = col / 3, c = col - a_ * 3;
        const float v = (a_ == 0) ? fu[0] : (a_ == 1) ? fu[1] : (a_ == 2) ? fu[2] : fu[3];
        const int atom = w * 16 + g * 4 + a_;
        out[OUT_FUNC + 3 * (abase + atom) + c] = v;
    }
}

extern "C" void kernel_launch(void* const* d_in, const int* in_sizes, int n_in,
                              void* d_out, int out_size, void* d_ws, size_t ws_size,
                              hipStream_t stream) {
    const float* nf     = (const float*)d_in[0];
    const float* energy = (const float*)d_in[1];
    const float* forces = (const float*)d_in[2];
    const float* stress = (const float*)d_in[3];
    const float* W1f    = (const float*)d_in[10];
    const float* b1f    = (const float*)d_in[11];
    const float* W2f    = (const float*)d_in[12];
    const float* b2f    = (const float*)d_in[13];
    const float* W3f    = (const float*)d_in[14];
    const float* b3f    = (const float*)d_in[15];
    float* out = (float*)d_out;

    dim3 grid(N_ATOMS / 64);   // 800 blocks
    funcert_kernel<<<grid, BLK, 0, stream>>>(nf, energy, forces, stress,
                                             W1f, b1f, W2f, b2f, W3f, b3f, out);
}